// Round 2
// baseline (2148.661 us; speedup 1.0000x reference)
//
#include <hip/hip_runtime.h>

// ============================================================================
// JumpODE (B=2048, T=128, H=64, N_STEPS=10) fused persistent kernel, gfx950.
//
// Parallel axis is batch only (T sequential, Euler sequential). One wave owns
// 16 batch rows. GEMMs computed in swapped orientation D = W @ X^T with
// mfma_f32_16x16x32_bf16 so that batch = D columns (lane&15) and the
// inter-layer activation exchange is a cheap wave-private LDS round trip
// (packed bf16 writes + 2x ds_read_b128, XOR-swizzled, lgkmcnt fences only,
// no barriers in the hot loop).
//
// Weights: W0/W1/W2 A-fragments resident in VGPRs (24 x bf16x8 = 96 VGPR).
// W_hh staged to LDS as swizzled bf16. m1 @ W_ih[:,1:]^T + b_ih + b_hh
// precomputed once per block into LDS (m1 = emb[marks[:,1,0]] is constant
// over t). Column-0 of W0/W_ih (the s_t / t inputs) are rank-1 and folded
// into epilogues. h/c state carried in fp32 registers.
//
// Fragment layouts (learn_hip verified, 16x16x32 bf16):
//   A: row m = lane&15,  k = (lane>>4)*8 + e   (8 bf16 / lane)
//   B: col n = lane&15,  k = (lane>>4)*8 + e
//   D: col n = lane&15,  row m = (lane>>4)*4 + reg
// ============================================================================

#define T_LEN 128

typedef float  f32x4  __attribute__((ext_vector_type(4)));
typedef __bf16 bf16x8 __attribute__((ext_vector_type(8)));
typedef __bf16 bf16x2 __attribute__((ext_vector_type(2)));

#define MFMA16(a, b, c) __builtin_amdgcn_mfma_f32_16x16x32_bf16((a), (b), (c), 0, 0, 0)

__device__ __forceinline__ void lds_fence() {
  asm volatile("s_waitcnt lgkmcnt(0)" ::: "memory");
}
__device__ __forceinline__ float rcp_f(float x) { return __builtin_amdgcn_rcpf(x); }
__device__ __forceinline__ float exp2_f(float x) { return __builtin_amdgcn_exp2f(x); }
__device__ __forceinline__ float log2_f(float x) { return __builtin_amdgcn_logf(x); }

constexpr float kL2E = 1.44269504088896340736f;
constexpr float kLN2 = 0.69314718055994530942f;

__device__ __forceinline__ float tanh_fast(float x) {
  // tanh(x) = 1 - 2/(1+e^{2x}); bounded inputs here, no overflow concern.
  float e = exp2_f(x * (2.0f * kL2E));
  return 1.0f - 2.0f * rcp_f(e + 1.0f);
}
__device__ __forceinline__ float sigm_fast(float x) {
  return rcp_f(1.0f + exp2_f(-kL2E * x));
}
__device__ __forceinline__ float softplus_fast(float x) {
  // max(x,0) + log1p(exp(-|x|)), stable both directions.
  float neg = log2_f(1.0f + exp2_f(-kL2E * fabsf(x))) * kLN2;
  return fmaxf(x, 0.0f) + neg;
}
__device__ __forceinline__ unsigned packbf(float a, float b) {
  bf16x2 v; v[0] = (__bf16)a; v[1] = (__bf16)b;   // RNE converts
  return __builtin_bit_cast(unsigned, v);
}

__launch_bounds__(64)
__global__ void jumpode_main(
    const float* __restrict__ times, const int* __restrict__ marks,
    const float* __restrict__ maskp, const float* __restrict__ W0,
    const float* __restrict__ b0,    const float* __restrict__ W1,
    const float* __restrict__ b1,    const float* __restrict__ W2,
    const float* __restrict__ b2,    const float* __restrict__ Wi,
    const float* __restrict__ bi,    const float* __restrict__ emb,
    const float* __restrict__ W_ih,  const float* __restrict__ W_hh,
    const float* __restrict__ b_ih,  const float* __restrict__ b_hh,
    float* __restrict__ out, float* __restrict__ ws)
{
  // ---- LDS (static, ~56 KB) ----
  __shared__ __align__(16) unsigned whh_l[256 * 32]; // bf16 pairs, swizzled, 32 KB
  __shared__ __align__(16) float    gm1_l[16 * 256]; // m1@Wih^T + b_ih + b_hh, swizzled, 16 KB
  __shared__ __align__(16) unsigned xbuf[16 * 32];   // activation X^T bf16, swizzled, 2 KB
  __shared__ __align__(16) float    b0_l[64];
  __shared__ __align__(16) float    b1_l[64];
  __shared__ __align__(16) float    b2_l[64];
  __shared__ __align__(16) float    w0c0_l[64];      // W0[:,0]
  __shared__ __align__(16) float    wihc0_l[256];    // W_ih[:,0]
  __shared__ __align__(16) float    emb16[16][64];

  const int tid  = threadIdx.x;   // 0..63
  const int lb   = tid & 15;      // batch column within wave
  const int q    = tid >> 4;      // lane quad 0..3
  const int row0 = blockIdx.x * 16;
  const int xsw  = lb & 7;        // xor-swizzle key (per batch column / row)
  const int xb_base = lb * 32;    // word base of this column's xbuf row

  // ---- stage small vectors ----
  b0_l[tid] = b0[tid]; b1_l[tid] = b1[tid]; b2_l[tid] = b2[tid];
  w0c0_l[tid] = W0[tid * 65];
  #pragma unroll
  for (int i = 0; i < 4; ++i) wihc0_l[tid + 64 * i] = W_ih[(tid + 64 * i) * 65];
  for (int i = 0; i < 16; ++i) {
    int mk = marks[(row0 + i) * T_LEN + 1];          // marks[:,1,0]
    emb16[i][tid] = emb[mk * 64 + tid];
  }
  // ---- stage W_hh -> bf16, row-chunk XOR swizzle: granule' = granule ^ (row&7)
  for (int i = 0; i < 128; ++i) {
    int idx = i * 64 + tid;                          // word index: row*32 + c2
    int rw = idx >> 5, c2 = idx & 31;
    unsigned pw = packbf(W_hh[rw * 64 + 2 * c2], W_hh[rw * 64 + 2 * c2 + 1]);
    int gr = c2 >> 2;
    whh_l[rw * 32 + (((gr ^ (rw & 7)) << 2)) + (c2 & 3)] = pw;
  }
  __syncthreads();

  // ---- gm1[b][g] = sum_k emb16[b][k]*W_ih[g][1+k] + b_ih[g] + b_hh[g] (swizzled)
  for (int i = 0; i < 4; ++i) {
    int g = tid + 64 * i;
    float acc[16];
    #pragma unroll
    for (int b = 0; b < 16; ++b) acc[b] = 0.0f;
    const float* wr = &W_ih[g * 65 + 1];
    for (int k = 0; k < 64; ++k) {
      float w = wr[k];
      #pragma unroll
      for (int b = 0; b < 16; ++b) acc[b] += w * emb16[b][k];
    }
    float bias = b_ih[g] + b_hh[g];
    int gg = g >> 2;
    #pragma unroll
    for (int b = 0; b < 16; ++b)
      gm1_l[b * 256 + (((gg ^ (b & 7)) << 2)) + (g & 3)] = acc[b] + bias;
  }

  // ---- W0/W1/W2 A-fragments into registers (bf16 RNE) ----
  bf16x8 w0f[4][2], w1f[4][2], w2f[4][2];
  #pragma unroll
  for (int jt = 0; jt < 4; ++jt) {
    #pragma unroll
    for (int kt = 0; kt < 2; ++kt) {
      const float* r0 = &W0[(jt * 16 + lb) * 65 + 1 + kt * 32 + q * 8]; // skip col 0
      const float* r1 = &W1[(jt * 16 + lb) * 64 +     kt * 32 + q * 8];
      const float* r2 = &W2[(jt * 16 + lb) * 64 +     kt * 32 + q * 8];
      bf16x8 a, bb, c;
      #pragma unroll
      for (int e = 0; e < 8; ++e) {
        a[e] = (__bf16)r0[e]; bb[e] = (__bf16)r1[e]; c[e] = (__bf16)r2[e];
      }
      w0f[jt][kt] = a; w1f[jt][kt] = bb; w2f[jt][kt] = c;
    }
  }
  // intensity weights for this lane's 16 feature slots (D-layout)
  f32x4 wiv[4];
  #pragma unroll
  for (int jt = 0; jt < 4; ++jt)
    #pragma unroll
    for (int r = 0; r < 4; ++r) wiv[jt][r] = Wi[jt * 16 + q * 4 + r];
  const float bi_s = bi[0];
  __syncthreads();

  // ---- state ----
  f32x4 hst[4], cst[4];
  #pragma unroll
  for (int jt = 0; jt < 4; ++jt) {
    hst[jt] = (f32x4){0.f, 0.f, 0.f, 0.f};
    cst[jt] = (f32x4){0.f, 0.f, 0.f, 0.f};
  }
  float nll_acc = 0.f, m_acc = 0.f;
  const float sel0 = (q == 0) ? 1.0f : 0.0f;   // avoid 4x duplicate accumulation

  // helpers as lambdas -----------------------------------------------------
  auto write_x = [&](const f32x4* v) {   // v[jt] in D-layout -> xbuf bf16
    #pragma unroll
    for (int jt = 0; jt < 4; ++jt) {
      int gr = (2 * jt + (q >> 1)) ^ xsw;
      int wb = xb_base + (gr << 2) + ((q & 1) << 1);
      xbuf[wb]     = packbf(v[jt][0], v[jt][1]);
      xbuf[wb + 1] = packbf(v[jt][2], v[jt][3]);
    }
  };
  auto read_bfrag = [&](int kt) -> bf16x8 {
    int gr = (kt * 4 + q) ^ xsw;
    return *(const bf16x8*)((const char*)xbuf + lb * 128 + gr * 16);
  };
  auto whh_frag = [&](int R, int kt) -> bf16x8 {
    int rw = R * 16 + lb;
    int gr = (kt * 4 + q) ^ xsw;   // (rw&7) == (lb&7)
    return *(const bf16x8*)((const char*)whh_l + rw * 128 + gr * 16);
  };
  auto ld_gm1 = [&](int R) -> f32x4 {
    int gr = (R * 4 + q) ^ xsw;
    return *(const f32x4*)((const char*)gm1_l + lb * 1024 + gr * 16);
  };

  // ---- time loop ----
  #pragma unroll 1
  for (int step = 0; step < T_LEN; ++step) {
    const float tb  = times[(row0 + lb) * T_LEN + step];
    const float dtt = 0.1f * tb;                 // dt * t
    f32x4 hh[4];
    #pragma unroll
    for (int jt = 0; jt < 4; ++jt) hh[jt] = hst[jt];
    float integ = 0.f;

    #pragma unroll 1
    for (int s = 0; s < 10; ++s) {
      // intensity(hh): full-precision dot, reduce over the 4 lane quads
      float part = 0.f;
      #pragma unroll
      for (int jt = 0; jt < 4; ++jt)
        #pragma unroll
        for (int r = 0; r < 4; ++r) part += wiv[jt][r] * hh[jt][r];
      part += __shfl_xor(part, 16);
      part += __shfl_xor(part, 32);
      integ += dtt * softplus_fast(part + bi_s);

      // stage hh -> X^T
      write_x(hh);
      lds_fence();
      bf16x8 Bf0 = read_bfrag(0), Bf1 = read_bfrag(1);
      const float st = (float)s * dtt;           // s*dt*t

      // layer 1: tanh(W0h @ hh^T + b0 + W0[:,0]*s_t)
      #pragma unroll
      for (int jt = 0; jt < 4; ++jt) {
        f32x4 acc = (f32x4){0.f, 0.f, 0.f, 0.f};
        acc = MFMA16(w0f[jt][0], Bf0, acc);
        acc = MFMA16(w0f[jt][1], Bf1, acc);
        f32x4 bv = *(const f32x4*)&b0_l[jt * 16 + q * 4];
        f32x4 cv = *(const f32x4*)&w0c0_l[jt * 16 + q * 4];
        f32x4 y;
        #pragma unroll
        for (int r = 0; r < 4; ++r) y[r] = tanh_fast(acc[r] + bv[r] + cv[r] * st);
        int gr = (2 * jt + (q >> 1)) ^ xsw;
        int wb = xb_base + (gr << 2) + ((q & 1) << 1);
        xbuf[wb] = packbf(y[0], y[1]); xbuf[wb + 1] = packbf(y[2], y[3]);
      }
      lds_fence();
      Bf0 = read_bfrag(0); Bf1 = read_bfrag(1);

      // layer 2
      #pragma unroll
      for (int jt = 0; jt < 4; ++jt) {
        f32x4 acc = (f32x4){0.f, 0.f, 0.f, 0.f};
        acc = MFMA16(w1f[jt][0], Bf0, acc);
        acc = MFMA16(w1f[jt][1], Bf1, acc);
        f32x4 bv = *(const f32x4*)&b1_l[jt * 16 + q * 4];
        f32x4 y;
        #pragma unroll
        for (int r = 0; r < 4; ++r) y[r] = tanh_fast(acc[r] + bv[r]);
        int gr = (2 * jt + (q >> 1)) ^ xsw;
        int wb = xb_base + (gr << 2) + ((q & 1) << 1);
        xbuf[wb] = packbf(y[0], y[1]); xbuf[wb + 1] = packbf(y[2], y[3]);
      }
      lds_fence();
      Bf0 = read_bfrag(0); Bf1 = read_bfrag(1);

      // layer 3 + Euler update: hh += dt*t*tanh(...)
      #pragma unroll
      for (int jt = 0; jt < 4; ++jt) {
        f32x4 acc = (f32x4){0.f, 0.f, 0.f, 0.f};
        acc = MFMA16(w2f[jt][0], Bf0, acc);
        acc = MFMA16(w2f[jt][1], Bf1, acc);
        f32x4 bv = *(const f32x4*)&b2_l[jt * 16 + q * 4];
        #pragma unroll
        for (int r = 0; r < 4; ++r) hh[jt][r] += dtt * tanh_fast(acc[r] + bv[r]);
      }
    } // euler

    // final intensity + nll
    float part = 0.f;
    #pragma unroll
    for (int jt = 0; jt < 4; ++jt)
      #pragma unroll
      for (int r = 0; r < 4; ++r) part += wiv[jt][r] * hh[jt][r];
    part += __shfl_xor(part, 16);
    part += __shfl_xor(part, 32);
    float inten = softplus_fast(part + bi_s);
    float nll = -(log2_f(inten) * kLN2) + integ;

    // store hidden = h_ode
    {
      size_t obase = 1 + (((size_t)(row0 + lb)) * T_LEN + step) * 64;
      #pragma unroll
      for (int jt = 0; jt < 4; ++jt)
        #pragma unroll
        for (int r = 0; r < 4; ++r) out[obase + jt * 16 + q * 4 + r] = hh[jt][r];
    }

    // LSTM: gates = W_ih[:,0]*t + gm1(+biases) + W_hh @ h_ode^T
    write_x(hh);
    lds_fence();
    bf16x8 Bf0 = read_bfrag(0), Bf1 = read_bfrag(1);
    #pragma unroll 1
    for (int j4 = 0; j4 < 4; ++j4) {
      f32x4 a_i = (f32x4){0.f,0.f,0.f,0.f}, a_f = a_i, a_g = a_i, a_o = a_i;
      a_i = MFMA16(whh_frag(j4 +  0, 0), Bf0, a_i);
      a_f = MFMA16(whh_frag(j4 +  4, 0), Bf0, a_f);
      a_g = MFMA16(whh_frag(j4 +  8, 0), Bf0, a_g);
      a_o = MFMA16(whh_frag(j4 + 12, 0), Bf0, a_o);
      a_i = MFMA16(whh_frag(j4 +  0, 1), Bf1, a_i);
      a_f = MFMA16(whh_frag(j4 +  4, 1), Bf1, a_f);
      a_g = MFMA16(whh_frag(j4 +  8, 1), Bf1, a_g);
      a_o = MFMA16(whh_frag(j4 + 12, 1), Bf1, a_o);
      f32x4 g_i = ld_gm1(j4 + 0),  g_f = ld_gm1(j4 + 4);
      f32x4 g_g = ld_gm1(j4 + 8),  g_o = ld_gm1(j4 + 12);
      f32x4 w_i = *(const f32x4*)&wihc0_l[(j4 +  0) * 16 + q * 4];
      f32x4 w_f = *(const f32x4*)&wihc0_l[(j4 +  4) * 16 + q * 4];
      f32x4 w_g = *(const f32x4*)&wihc0_l[(j4 +  8) * 16 + q * 4];
      f32x4 w_o = *(const f32x4*)&wihc0_l[(j4 + 12) * 16 + q * 4];
      #pragma unroll
      for (int r = 0; r < 4; ++r) {
        float pi = a_i[r] + g_i[r] + w_i[r] * tb;
        float pf = a_f[r] + g_f[r] + w_f[r] * tb;
        float pg = a_g[r] + g_g[r] + w_g[r] * tb;
        float po = a_o[r] + g_o[r] + w_o[r] * tb;
        float ig = sigm_fast(pi), fg = sigm_fast(pf);
        float gg = tanh_fast(pg), og = sigm_fast(po);
        float cn = fg * cst[j4][r] + ig * gg;
        cst[j4][r] = cn;
        hst[j4][r] = og * tanh_fast(cn);
      }
    }

    float mval = maskp[(row0 + lb) * T_LEN + step];
    nll_acc += sel0 * mval * nll;
    m_acc   += sel0 * mval;
  } // time loop

  // loss accumulation
  #pragma unroll
  for (int off = 1; off < 64; off <<= 1) {
    nll_acc += __shfl_xor(nll_acc, off);
    m_acc   += __shfl_xor(m_acc, off);
  }
  if (tid == 0) {
    atomicAdd(&ws[0], nll_acc);
    atomicAdd(&ws[1], m_acc);
  }
}

__global__ void jumpode_fin(const float* __restrict__ ws, float* __restrict__ out) {
  if (threadIdx.x == 0 && blockIdx.x == 0) out[0] = ws[0] / ws[1];
}

extern "C" void kernel_launch(void* const* d_in, const int* in_sizes, int n_in,
                              void* d_out, int out_size, void* d_ws, size_t ws_size,
                              hipStream_t stream) {
  (void)in_sizes; (void)n_in; (void)out_size; (void)ws_size;
  const float* times = (const float*)d_in[0];
  const int*   marks = (const int*)  d_in[1];
  const float* maskp = (const float*)d_in[2];
  const float* W0    = (const float*)d_in[3];
  const float* b0    = (const float*)d_in[4];
  const float* W1    = (const float*)d_in[5];
  const float* b1    = (const float*)d_in[6];
  const float* W2    = (const float*)d_in[7];
  const float* b2    = (const float*)d_in[8];
  const float* Wi    = (const float*)d_in[9];
  const float* bi    = (const float*)d_in[10];
  const float* emb   = (const float*)d_in[11];
  const float* W_ih  = (const float*)d_in[12];
  const float* W_hh  = (const float*)d_in[13];
  const float* b_ih  = (const float*)d_in[14];
  const float* b_hh  = (const float*)d_in[15];
  float* out = (float*)d_out;
  float* ws  = (float*)d_ws;

  (void)hipMemsetAsync(d_ws, 0, 2 * sizeof(float), stream);
  jumpode_main<<<dim3(128), dim3(64), 0, stream>>>(
      times, marks, maskp, W0, b0, W1, b1, W2, b2, Wi, bi, emb,
      W_ih, W_hh, b_ih, b_hh, out, ws);
  jumpode_fin<<<dim3(1), dim3(64), 0, stream>>>(ws, out);
}

// Round 3
// 1005.937 us; speedup vs baseline: 2.1360x; 2.1360x over previous
//
#include <hip/hip_runtime.h>

// ============================================================================
// JumpODE (B=2048, T=128, H=64, N_STEPS=10) fused persistent kernel, gfx950.
// Round 3: 4-wave N-split, 8 batch rows / block, 256 blocks (all 256 CUs).
//
// Wave w of each 256-thread block owns output features [16w, 16w+16) of every
// GEMM. Per layer: 2 dependent MFMAs + 4-tanh epilogue per lane, then a
// block-wide LDS exchange (double-buffered xbuf, ONE __syncthreads per
// layer). Batch columns 8..15 of the MFMA tile mirror rows 0..7 (b&7), so
// the chain length is unchanged but the whole chip is used.
//
// Fragment layouts (16x16x32 bf16, learn_hip verified):
//   A: row m = lane&15,  k = (lane>>4)*8 + e
//   B: col n = lane&15,  k = (lane>>4)*8 + e
//   D: col n = lane&15,  row m = (lane>>4)*4 + reg
// ============================================================================

#define T_LEN 128

typedef float  f32x4  __attribute__((ext_vector_type(4)));
typedef __bf16 bf16x8 __attribute__((ext_vector_type(8)));
typedef __bf16 bf16x2 __attribute__((ext_vector_type(2)));

#define MFMA16(a, b, c) __builtin_amdgcn_mfma_f32_16x16x32_bf16((a), (b), (c), 0, 0, 0)

__device__ __forceinline__ float rcp_f(float x) { return __builtin_amdgcn_rcpf(x); }
__device__ __forceinline__ float exp2_f(float x) { return __builtin_amdgcn_exp2f(x); }
__device__ __forceinline__ float log2_f(float x) { return __builtin_amdgcn_logf(x); }

constexpr float kL2E = 1.44269504088896340736f;
constexpr float kLN2 = 0.69314718055994530942f;

__device__ __forceinline__ float tanh_fast(float x) {
  float e = exp2_f(x * (2.0f * kL2E));
  return 1.0f - 2.0f * rcp_f(e + 1.0f);
}
__device__ __forceinline__ float sigm_fast(float x) {
  return rcp_f(1.0f + exp2_f(-kL2E * x));
}
__device__ __forceinline__ float softplus_fast(float x) {
  float neg = log2_f(1.0f + exp2_f(-kL2E * fabsf(x))) * kLN2;
  return fmaxf(x, 0.0f) + neg;
}
__device__ __forceinline__ unsigned packbf(float a, float b) {
  bf16x2 v; v[0] = (__bf16)a; v[1] = (__bf16)b;   // RNE
  return __builtin_bit_cast(unsigned, v);
}

__launch_bounds__(256)
__global__ void jumpode_main(
    const float* __restrict__ times, const int* __restrict__ marks,
    const float* __restrict__ maskp, const float* __restrict__ W0,
    const float* __restrict__ b0,    const float* __restrict__ W1,
    const float* __restrict__ b1,    const float* __restrict__ W2,
    const float* __restrict__ b2,    const float* __restrict__ Wi,
    const float* __restrict__ bi,    const float* __restrict__ emb,
    const float* __restrict__ W_ih,  const float* __restrict__ W_hh,
    const float* __restrict__ b_ih,  const float* __restrict__ b_hh,
    float* __restrict__ out, float* __restrict__ ws)
{
  // ---- LDS (~48 KB) ----
  __shared__ __align__(16) unsigned whh_l[256 * 32];   // bf16 pairs, swizzled, 32 KB
  __shared__ __align__(16) float    gm1_l[8 * 256];    // m1@Wih^T + biases, swizzled, 8 KB
  __shared__ __align__(16) unsigned xbuf[2][16 * 32];  // activation X^T bf16, 2x2 KB
  __shared__ __align__(16) float    pint[16 * 4];      // intensity partials [b][w]
  __shared__ __align__(16) float    b0_l[64], b1_l[64], b2_l[64];
  __shared__ __align__(16) float    w0c0_l[64];        // W0[:,0]
  __shared__ __align__(16) float    wihc0_l[256];      // W_ih[:,0]
  __shared__ __align__(16) float    emb16[8][64];

  const int tid = threadIdx.x;          // 0..255
  const int wv  = tid >> 6;             // wave id = feature block jt
  const int l   = tid & 63;
  const int b   = l & 15;               // MFMA batch column
  const int q   = l >> 4;               // lane quad
  const int bm  = b & 7;                // real batch row within block
  const int row = blockIdx.x * 8 + bm;  // global batch row (always in-bounds)
  const int xsw = b & 7;                // xor-swizzle key

  // ---- staging (256 threads) ----
  if (tid < 64) {
    b0_l[tid] = b0[tid]; b1_l[tid] = b1[tid]; b2_l[tid] = b2[tid];
    w0c0_l[tid] = W0[tid * 65];
  }
  wihc0_l[tid] = W_ih[tid * 65];
  for (int idx = tid; idx < 512; idx += 256) {
    int rr = idx >> 6, cc = idx & 63;
    int mk = marks[(blockIdx.x * 8 + rr) * T_LEN + 1];
    emb16[rr][cc] = emb[mk * 64 + cc];
  }
  #pragma unroll 4
  for (int i = 0; i < 32; ++i) {                      // W_hh -> bf16 swizzled
    int idx = i * 256 + tid;                          // word: row*32 + c2
    int rw = idx >> 5, c2 = idx & 31;
    unsigned pw = packbf(W_hh[rw * 64 + 2 * c2], W_hh[rw * 64 + 2 * c2 + 1]);
    int gr = c2 >> 2;
    whh_l[rw * 32 + ((gr ^ (rw & 7)) << 2) + (c2 & 3)] = pw;
  }
  __syncthreads();

  // gm1[b][g] = emb16[b] . W_ih[g,1:] + b_ih[g] + b_hh[g]  (one gate per thread)
  {
    int g = tid;
    float acc[8];
    #pragma unroll
    for (int bb = 0; bb < 8; ++bb) acc[bb] = 0.0f;
    const float* wr = &W_ih[g * 65 + 1];
    for (int k = 0; k < 64; ++k) {
      float w = wr[k];
      #pragma unroll
      for (int bb = 0; bb < 8; ++bb) acc[bb] += w * emb16[bb][k];
    }
    float bias = b_ih[g] + b_hh[g];
    int gg = g >> 2;
    #pragma unroll
    for (int bb = 0; bb < 8; ++bb)
      gm1_l[bb * 256 + ((gg ^ bb) << 2) + (g & 3)] = acc[bb] + bias;
  }

  // ---- per-wave weight fragments (features 16wv..16wv+15) ----
  bf16x8 w0f[2], w1f[2], w2f[2];
  {
    const int fm = 16 * wv + b;         // A row = feature
    #pragma unroll
    for (int kt = 0; kt < 2; ++kt) {
      const float* r0 = &W0[fm * 65 + 1 + kt * 32 + q * 8];
      const float* r1 = &W1[fm * 64 +     kt * 32 + q * 8];
      const float* r2 = &W2[fm * 64 +     kt * 32 + q * 8];
      bf16x8 a, bb, c;
      #pragma unroll
      for (int e = 0; e < 8; ++e) {
        a[e] = (__bf16)r0[e]; bb[e] = (__bf16)r1[e]; c[e] = (__bf16)r2[e];
      }
      w0f[kt] = a; w1f[kt] = bb; w2f[kt] = c;
    }
  }
  f32x4 wiv;
  #pragma unroll
  for (int r = 0; r < 4; ++r) wiv[r] = Wi[16 * wv + 4 * q + r];
  const float bi_s = bi[0];
  const f32x4 b0v = *(const f32x4*)&b0_l[16 * wv + 4 * q];
  const f32x4 b1v = *(const f32x4*)&b1_l[16 * wv + 4 * q];
  const f32x4 b2v = *(const f32x4*)&b2_l[16 * wv + 4 * q];
  const f32x4 c0v = *(const f32x4*)&w0c0_l[16 * wv + 4 * q];
  __syncthreads();

  // helpers ----------------------------------------------------------------
  auto write_x = [&](unsigned* buf, const f32x4 v) {
    int gr = (2 * wv + (q >> 1)) ^ xsw;
    int wb = b * 32 + (gr << 2) + ((q & 1) << 1);
    buf[wb]     = packbf(v[0], v[1]);
    buf[wb + 1] = packbf(v[2], v[3]);
  };
  auto read_bfrag = [&](const unsigned* buf, int kt) -> bf16x8 {
    int gr = (kt * 4 + q) ^ xsw;
    return *(const bf16x8*)((const char*)buf + b * 128 + gr * 16);
  };
  auto whh_frag = [&](int R, int kt) -> bf16x8 {
    int rw = R * 16 + b;
    int gr = (kt * 4 + q) ^ xsw;
    return *(const bf16x8*)((const char*)whh_l + rw * 128 + gr * 16);
  };
  auto ld_gm1 = [&](int R) -> f32x4 {
    int gr = (R * 4 + q) ^ xsw;
    return *(const f32x4*)((const char*)gm1_l + bm * 1024 + gr * 16);
  };
  auto isect_partial = [&](const f32x4 v) {
    float part = wiv[0] * v[0] + wiv[1] * v[1] + wiv[2] * v[2] + wiv[3] * v[3];
    part += __shfl_xor(part, 16);
    part += __shfl_xor(part, 32);
    if (l < 16) pint[b * 4 + wv] = part;   // q==0 lanes publish
  };

  // ---- state ----
  f32x4 hst = (f32x4){0.f, 0.f, 0.f, 0.f};
  f32x4 cst = (f32x4){0.f, 0.f, 0.f, 0.f};
  float nll_acc = 0.f, m_acc = 0.f;
  const float sel0 = (q == 0 && b < 8) ? 1.0f : 0.0f;
  int xp = 0;

  #pragma unroll 1
  for (int step = 0; step < T_LEN; ++step) {
    const float tb  = times[row * T_LEN + step];
    const float dtt = 0.1f * tb;
    f32x4 hh = hst;
    float integ = 0.f;

    #pragma unroll 1
    for (int s = 0; s < 10; ++s) {
      // exchange 1: hh (+ intensity partials)
      isect_partial(hh);
      write_x(xbuf[xp], hh);
      __syncthreads();
      bf16x8 Bf0 = read_bfrag(xbuf[xp], 0), Bf1 = read_bfrag(xbuf[xp], 1);
      xp ^= 1;
      if (wv == 0) {
        f32x4 p = *(const f32x4*)&pint[b * 4];
        integ += dtt * softplus_fast(p[0] + p[1] + p[2] + p[3] + bi_s);
      }
      const float st = (float)s * dtt;

      // layer 1
      f32x4 acc = (f32x4){0.f, 0.f, 0.f, 0.f};
      acc = MFMA16(w0f[0], Bf0, acc);
      acc = MFMA16(w0f[1], Bf1, acc);
      f32x4 y;
      #pragma unroll
      for (int r = 0; r < 4; ++r) y[r] = tanh_fast(acc[r] + b0v[r] + c0v[r] * st);
      write_x(xbuf[xp], y);
      __syncthreads();
      Bf0 = read_bfrag(xbuf[xp], 0); Bf1 = read_bfrag(xbuf[xp], 1);
      xp ^= 1;

      // layer 2
      acc = (f32x4){0.f, 0.f, 0.f, 0.f};
      acc = MFMA16(w1f[0], Bf0, acc);
      acc = MFMA16(w1f[1], Bf1, acc);
      #pragma unroll
      for (int r = 0; r < 4; ++r) y[r] = tanh_fast(acc[r] + b1v[r]);
      write_x(xbuf[xp], y);
      __syncthreads();
      Bf0 = read_bfrag(xbuf[xp], 0); Bf1 = read_bfrag(xbuf[xp], 1);
      xp ^= 1;

      // layer 3 + Euler update
      acc = (f32x4){0.f, 0.f, 0.f, 0.f};
      acc = MFMA16(w2f[0], Bf0, acc);
      acc = MFMA16(w2f[1], Bf1, acc);
      #pragma unroll
      for (int r = 0; r < 4; ++r) hh[r] += dtt * tanh_fast(acc[r] + b2v[r]);
    } // euler

    // final intensity partials + h_ode exchange + store
    isect_partial(hh);
    write_x(xbuf[xp], hh);
    if (b < 8) {
      size_t obase = 1 + (((size_t)row) * T_LEN + step) * 64 + 16 * wv + 4 * q;
      out[obase + 0] = hh[0]; out[obase + 1] = hh[1];
      out[obase + 2] = hh[2]; out[obase + 3] = hh[3];
    }
    __syncthreads();
    bf16x8 Bf0 = read_bfrag(xbuf[xp], 0), Bf1 = read_bfrag(xbuf[xp], 1);
    xp ^= 1;

    float nll = 0.f;
    if (wv == 0) {
      f32x4 p = *(const f32x4*)&pint[b * 4];
      float inten = softplus_fast(p[0] + p[1] + p[2] + p[3] + bi_s);
      nll = -(log2_f(inten) * kLN2) + integ;
    }

    // LSTM gates: wave w computes gates i,f,g,o for features 16wv..16wv+15
    f32x4 ga[4];
    #pragma unroll
    for (int g = 0; g < 4; ++g) {
      const int Rb = 4 * g + wv;
      f32x4 a = (f32x4){0.f, 0.f, 0.f, 0.f};
      a = MFMA16(whh_frag(Rb, 0), Bf0, a);
      a = MFMA16(whh_frag(Rb, 1), Bf1, a);
      f32x4 gm = ld_gm1(Rb);
      f32x4 wc = *(const f32x4*)&wihc0_l[Rb * 16 + q * 4];
      #pragma unroll
      for (int r = 0; r < 4; ++r) ga[g][r] = a[r] + gm[r] + wc[r] * tb;
    }
    #pragma unroll
    for (int r = 0; r < 4; ++r) {
      float ig = sigm_fast(ga[0][r]), fg = sigm_fast(ga[1][r]);
      float gg = tanh_fast(ga[2][r]), og = sigm_fast(ga[3][r]);
      float cn = fg * cst[r] + ig * gg;
      cst[r] = cn;
      hst[r] = og * tanh_fast(cn);
    }

    if (wv == 0) {
      float mval = maskp[row * T_LEN + step];
      nll_acc += sel0 * mval * nll;
      m_acc   += sel0 * mval;
    }
  } // time loop

  if (wv == 0) {
    #pragma unroll
    for (int off = 1; off < 64; off <<= 1) {
      nll_acc += __shfl_xor(nll_acc, off);
      m_acc   += __shfl_xor(m_acc, off);
    }
    if (tid == 0) {
      atomicAdd(&ws[0], nll_acc);
      atomicAdd(&ws[1], m_acc);
    }
  }
}

__global__ void jumpode_fin(const float* __restrict__ ws, float* __restrict__ out) {
  if (threadIdx.x == 0 && blockIdx.x == 0) out[0] = ws[0] / ws[1];
}

extern "C" void kernel_launch(void* const* d_in, const int* in_sizes, int n_in,
                              void* d_out, int out_size, void* d_ws, size_t ws_size,
                              hipStream_t stream) {
  (void)in_sizes; (void)n_in; (void)out_size; (void)ws_size;
  const float* times = (const float*)d_in[0];
  const int*   marks = (const int*)  d_in[1];
  const float* maskp = (const float*)d_in[2];
  const float* W0    = (const float*)d_in[3];
  const float* b0    = (const float*)d_in[4];
  const float* W1    = (const float*)d_in[5];
  const float* b1    = (const float*)d_in[6];
  const float* W2    = (const float*)d_in[7];
  const float* b2    = (const float*)d_in[8];
  const float* Wi    = (const float*)d_in[9];
  const float* bi    = (const float*)d_in[10];
  const float* emb   = (const float*)d_in[11];
  const float* W_ih  = (const float*)d_in[12];
  const float* W_hh  = (const float*)d_in[13];
  const float* b_ih  = (const float*)d_in[14];
  const float* b_hh  = (const float*)d_in[15];
  float* out = (float*)d_out;
  float* ws  = (float*)d_ws;

  (void)hipMemsetAsync(d_ws, 0, 2 * sizeof(float), stream);
  jumpode_main<<<dim3(256), dim3(256), 0, stream>>>(
      times, marks, maskp, W0, b0, W1, b1, W2, b2, Wi, bi, emb,
      W_ih, W_hh, b_ih, b_hh, out, ws);
  jumpode_fin<<<dim3(1), dim3(64), 0, stream>>>(ws, out);
}